// Round 1
// 3444.829 us; speedup vs baseline: 1.5740x; 1.5740x over previous
//
#include <hip/hip_runtime.h>

#define TT 512
#define BB 32
#define II 512
#define HH 1024
#define G3 3072
#define TBH (TT * BB * HH) /* 16777216 */

__device__ __forceinline__ float sigmoidf_(float x) {
    return 1.f / (1.f + __expf(-x));
}
__device__ __forceinline__ float tanh_fast(float x) {
    float e2 = __expf(2.f * x);
    return 1.f - 2.f / (e2 + 1.f);
}

/* ---- gi = A(M x 512) @ w_ih(512 x 3072) + b_ih ---- */
__global__ __launch_bounds__(256) void k_gi_gemm(const float* __restrict__ A,
                                                 const float* __restrict__ B,
                                                 const float* __restrict__ bias,
                                                 float* __restrict__ C, int M) {
    __shared__ float As[8][128];
    __shared__ float Bs[8][128];
    int tid = threadIdx.x;
    int m0 = blockIdx.x * 128;
    int n0 = blockIdx.y * 128;
    int tx = tid & 15, ty = tid >> 4;
    int rowA = tid >> 1, kA = (tid & 1) * 4;
    int kB = tid >> 5, cB = (tid & 31) * 4;
    float acc[8][8] = {};
    for (int k0 = 0; k0 < 512; k0 += 8) {
        int rg = m0 + rowA;
        if (rg > M - 1) rg = M - 1;
        float4 a4 = *(const float4*)(A + (size_t)rg * 512 + k0 + kA);
        float4 b4 = *(const float4*)(B + (size_t)(k0 + kB) * G3 + n0 + cB);
        __syncthreads();
        As[kA + 0][rowA] = a4.x;
        As[kA + 1][rowA] = a4.y;
        As[kA + 2][rowA] = a4.z;
        As[kA + 3][rowA] = a4.w;
        *(float4*)&Bs[kB][cB] = b4;
        __syncthreads();
#pragma unroll
        for (int kk = 0; kk < 8; ++kk) {
            float4 a0 = *(const float4*)&As[kk][ty * 8];
            float4 a1 = *(const float4*)&As[kk][ty * 8 + 4];
            float4 b0 = *(const float4*)&Bs[kk][tx * 8];
            float4 b1 = *(const float4*)&Bs[kk][tx * 8 + 4];
            float av[8] = {a0.x, a0.y, a0.z, a0.w, a1.x, a1.y, a1.z, a1.w};
            float bv[8] = {b0.x, b0.y, b0.z, b0.w, b1.x, b1.y, b1.z, b1.w};
#pragma unroll
            for (int i = 0; i < 8; ++i)
#pragma unroll
                for (int j = 0; j < 8; ++j) acc[i][j] += av[i] * bv[j];
        }
    }
    float4 bi0 = *(const float4*)(bias + n0 + tx * 8);
    float4 bi1 = *(const float4*)(bias + n0 + tx * 8 + 4);
    float bb[8] = {bi0.x, bi0.y, bi0.z, bi0.w, bi1.x, bi1.y, bi1.z, bi1.w};
#pragma unroll
    for (int i = 0; i < 8; ++i) {
        int row = m0 + ty * 8 + i;
        if (row < M) {
            float4 s0 = {acc[i][0] + bb[0], acc[i][1] + bb[1], acc[i][2] + bb[2], acc[i][3] + bb[3]};
            float4 s1 = {acc[i][4] + bb[4], acc[i][5] + bb[5], acc[i][6] + bb[6], acc[i][7] + bb[7]};
            *(float4*)(C + (size_t)row * G3 + n0 + tx * 8) = s0;
            *(float4*)(C + (size_t)row * G3 + n0 + tx * 8 + 4) = s1;
        }
    }
}

/* ---- persistent recurrent kernel, v2: flag-free self-signaling ----
   grid 256 = 64 h-col-groups x 4 batch-octets; block 512 thr = 8 waves.
   h(t) lives directly in out[t] (first copy). out[0..TBH) is pre-memset to
   0xFFFFFFFF (float NaN). Since |h| < 1 always (convex combo of tanh
   outputs from h0=0), the sentinel is unreachable as a real value, so the
   DATA is its own readiness flag: producers do ONE relaxed agent-scope
   store per value; consumers issue their 8 staging loads in parallel and
   re-issue only the ones still reading sentinel. This removes the
   vmcnt(0) drain, the flag store->poll round trip, the separate
   post-detect staging pass, and one barrier per step (3 barriers/step,
   zero fences). */
__global__ __launch_bounds__(512, 2) void k_persist(const float* __restrict__ w_hh,
                                                    const float* __restrict__ gi,
                                                    const float* __restrict__ pad,
                                                    const float* __restrict__ b_hh,
                                                    float* __restrict__ out,
                                                    int t0, int ct) {
    __shared__ float h_s[9216];   /* [b 8][row 32] rows of 36 (32 + 4 pad) */
    __shared__ float part[13888]; /* [cg 16] stride 868: [(g,b) 24] stride 36: [ks 32] */

    int tid = threadIdx.x;
    int cg = tid & 15, ks = tid >> 4;
    int hg = blockIdx.x & 63, boct = blockIdx.x >> 6;
    int hc0 = hg << 4;
    int b0 = boct << 3;
    int col = hc0 + cg;

    /* one-time weight load into float4 regs */
    float4 w0q[8], w1q[8], w2q[8];
    {
        const float* wb = w_hh + (size_t)(ks * 32) * G3 + col;
#pragma unroll
        for (int j = 0; j < 8; ++j) {
            w0q[j].x = wb[(j * 4 + 0) * G3];
            w0q[j].y = wb[(j * 4 + 1) * G3];
            w0q[j].z = wb[(j * 4 + 2) * G3];
            w0q[j].w = wb[(j * 4 + 3) * G3];
            w1q[j].x = wb[(j * 4 + 0) * G3 + HH];
            w1q[j].y = wb[(j * 4 + 1) * G3 + HH];
            w1q[j].z = wb[(j * 4 + 2) * G3 + HH];
            w1q[j].w = wb[(j * 4 + 3) * G3 + HH];
            w2q[j].x = wb[(j * 4 + 0) * G3 + 2 * HH];
            w2q[j].y = wb[(j * 4 + 1) * G3 + 2 * HH];
            w2q[j].z = wb[(j * 4 + 2) * G3 + 2 * HH];
            w2q[j].w = wb[(j * 4 + 3) * G3 + 2 * HH];
        }
    }
    /* gate-thread constants (tid<128: gcg=cg, b2=tid>>4) */
    int b2 = tid >> 4;
    int bg = b0 + b2;
    float bhr = 0.f, bhz = 0.f, bhn = 0.f;
    if (tid < 128) {
        bhr = b_hh[col];
        bhz = b_hh[col + HH];
        bhn = b_hh[col + 2 * HH];
    }

    /* staging geometry: wave sb stages batch sb; 8x 8-byte relaxed atomic
       loads per thread, lane-contiguous (512 B/instr coalesced) */
    int sb = tid >> 6;
    int lane = tid & 63;
    int srow0 = lane >> 4;
    int scol = (lane & 15) * 2;

    for (int s = 0; s < ct; ++s) {
        int t = t0 + s;

        /* prefetch gi + pad for this step (consumed in gates phase) */
        float gir = 0.f, giz = 0.f, gin = 0.f, pv = 0.f;
        if (tid < 128) {
            const float* gp = gi + ((size_t)s * BB + bg) * G3 + col;
            gir = gp[0];
            giz = gp[HH];
            gin = gp[2 * HH];
            pv = pad[t * BB + bg];
        }

        /* stage h(t-1) -> h_s. t==0: zeros (h0=0), no loads. Else: poll
           out[t-1] directly; sentinel 0xFFFFFFFF marks not-yet-written. */
        if (t == 0) {
#pragma unroll
            for (int i = 0; i < 8; ++i)
                *(unsigned long long*)&h_s[((sb << 5) + 4 * i + srow0) * 36 + scol] = 0ull;
        } else {
            const unsigned long long* hp =
                (const unsigned long long*)(out + (size_t)(t - 1) * (BB * HH) +
                                            (size_t)(b0 + sb) * HH) + lane;
            unsigned long long v[8];
#pragma unroll
            for (int i = 0; i < 8; ++i)
                v[i] = __hip_atomic_load(hp + i * 64, __ATOMIC_RELAXED,
                                         __HIP_MEMORY_SCOPE_AGENT);
            for (;;) {
                int bad = 0;
#pragma unroll
                for (int i = 0; i < 8; ++i) {
                    unsigned lo = (unsigned)v[i];
                    unsigned hi = (unsigned)(v[i] >> 32);
                    if (lo == 0xFFFFFFFFu || hi == 0xFFFFFFFFu) bad |= (1 << i);
                }
                if (!bad) break;
                __builtin_amdgcn_s_sleep(1);
#pragma unroll
                for (int i = 0; i < 8; ++i)
                    if (bad & (1 << i))
                        v[i] = __hip_atomic_load(hp + i * 64, __ATOMIC_RELAXED,
                                                 __HIP_MEMORY_SCOPE_AGENT);
            }
#pragma unroll
            for (int i = 0; i < 8; ++i)
                *(unsigned long long*)&h_s[((sb << 5) + 4 * i + srow0) * 36 + scol] = v[i];
        }
        __syncthreads();

        /* FMA phase */
        float acc0[8], acc1[8], acc2[8];
#pragma unroll
        for (int b = 0; b < 8; ++b) {
            const float4* hp4 = (const float4*)&h_s[((b << 5) + ks) * 36];
            float a0 = 0.f, a1 = 0.f, a2 = 0.f;
#pragma unroll
            for (int q = 0; q < 8; ++q) {
                float4 h4 = hp4[q];
                a0 += w0q[q].x * h4.x + w0q[q].y * h4.y + w0q[q].z * h4.z + w0q[q].w * h4.w;
                a1 += w1q[q].x * h4.x + w1q[q].y * h4.y + w1q[q].z * h4.z + w1q[q].w * h4.w;
                a2 += w2q[q].x * h4.x + w2q[q].y * h4.y + w2q[q].z * h4.z + w2q[q].w * h4.w;
            }
            acc0[b] = a0;
            acc1[b] = a1;
            acc2[b] = a2;
        }
        {
            float* pb = &part[cg * 868 + ks];
#pragma unroll
            for (int b = 0; b < 8; ++b) {
                pb[b * 36] = acc0[b];
                pb[(8 + b) * 36] = acc1[b];
                pb[(16 + b) * 36] = acc2[b];
            }
        }
        __syncthreads();

        /* gates: 128 threads each reduce their own 3 partial rows */
        if (tid < 128) {
            float gh0, gh1, gh2;
#pragma unroll
            for (int g = 0; g < 3; ++g) {
                const float4* pp = (const float4*)&part[cg * 868 + (g * 8 + b2) * 36];
                float4 v = pp[0];
#pragma unroll
                for (int q = 1; q < 8; ++q) {
                    float4 u = pp[q];
                    v.x += u.x; v.y += u.y; v.z += u.z; v.w += u.w;
                }
                float sv = v.x + v.y + v.z + v.w;
                if (g == 0) gh0 = sv;
                else if (g == 1) gh1 = sv;
                else gh2 = sv;
            }
            float hprev = h_s[((b2 << 5) + (col >> 5)) * 36 + (col & 31)];
            float r = sigmoidf_(gir + gh0 + bhr);
            float z = sigmoidf_(giz + gh1 + bhz);
            float n = tanh_fast(gin + r * (gh2 + bhn));
            float hnew = (1.f - z) * n + z * hprev;
            hnew = pv * hprev + (1.f - pv) * hnew;
            size_t oo = (size_t)t * (BB * HH) + (size_t)bg * HH + col;
            /* the self-signaling store: straight to L3, consumers poll it */
            __hip_atomic_store(out + oo, hnew, __ATOMIC_RELAXED,
                               __HIP_MEMORY_SCOPE_AGENT);
            out[(size_t)TBH + oo] = hnew;
        }
        /* WAR guard: all of h_s/part consumed before next step restages */
        __syncthreads();
    }
}

/* ---- emergency fallback if workspace is tiny: fused, slow, correct ---- */
__global__ __launch_bounds__(256) void k_step_slow(const float* __restrict__ x_t,
                                                   const float* __restrict__ pad_t,
                                                   const float* __restrict__ w_ih,
                                                   const float* __restrict__ w_hh,
                                                   const float* __restrict__ b_ih,
                                                   const float* __restrict__ b_hh,
                                                   const float* __restrict__ h_in,
                                                   float* __restrict__ h_out,
                                                   float* __restrict__ out, int t) {
    int g = blockIdx.x * 256 + threadIdx.x;
    int b = g >> 10, j = g & 1023;
    float gir = b_ih[j], giz = b_ih[j + HH], gin = b_ih[j + 2 * HH];
    for (int k = 0; k < II; ++k) {
        float xv = x_t[b * II + k];
        const float* wr = w_ih + (size_t)k * G3;
        gir += xv * wr[j];
        giz += xv * wr[j + HH];
        gin += xv * wr[j + 2 * HH];
    }
    float ghr = b_hh[j], ghz = b_hh[j + HH], ghn = b_hh[j + 2 * HH];
    for (int k = 0; k < HH; ++k) {
        float hv = h_in[b * HH + k];
        const float* wr = w_hh + (size_t)k * G3;
        ghr += hv * wr[j];
        ghz += hv * wr[j + HH];
        ghn += hv * wr[j + 2 * HH];
    }
    float hprev = h_in[b * HH + j];
    float p = pad_t[b];
    float r = sigmoidf_(gir + ghr);
    float z = sigmoidf_(giz + ghz);
    float n = tanh_fast(gin + r * ghn);
    float hnew = (1.f - z) * n + z * hprev;
    hnew = p * hprev + (1.f - p) * hnew;
    size_t o = (size_t)b * HH + j;
    h_out[o] = hnew;
    size_t oo = (size_t)t * (BB * HH) + o;
    out[oo] = hnew;
    out[(size_t)TBH + oo] = hnew;
}

extern "C" void kernel_launch(void* const* d_in, const int* in_sizes, int n_in,
                              void* d_out, int out_size, void* d_ws, size_t ws_size,
                              hipStream_t stream) {
    const float* x    = (const float*)d_in[0];
    const float* pad  = (const float*)d_in[1];
    const float* w_ih = (const float*)d_in[2];
    const float* w_hh = (const float*)d_in[3];
    const float* b_ih = (const float*)d_in[4];
    const float* b_hh = (const float*)d_in[5];
    float* out = (float*)d_out;

    char* wsb = (char*)d_ws;
    float* hA = (float*)wsb;            /* 128 KB (fallback only) */
    float* hB = (float*)(wsb + 131072); /* 128 KB (fallback only) */
    float* gi = (float*)(wsb + 262144); /* Tc * 32 * 3072 * 4 B */

    long long cap = (long long)ws_size - 262144LL;
    int Tc = cap > 0 ? (int)(cap / 393216LL) : 0;
    if (Tc > TT) Tc = TT;

    if (Tc >= 1) {
        /* sentinel-fill the h-history region (first copy of out): 0xFFFFFFFF
           is float NaN, unreachable since |h| < 1 always */
        hipMemsetAsync(out, 0xFF, (size_t)TBH * 4, stream);
        for (int t0 = 0; t0 < TT; t0 += Tc) {
            int ctn = (TT - t0 < Tc) ? (TT - t0) : Tc;
            int M = ctn * BB;
            dim3 g((M + 127) / 128, 24);
            k_gi_gemm<<<g, 256, 0, stream>>>(x + (size_t)t0 * BB * II, w_ih, b_ih, gi, M);
            k_persist<<<256, 512, 0, stream>>>(w_hh, gi, pad, b_hh, out, t0, ctn);
        }
    } else {
        hipMemsetAsync(hA, 0, 131072, stream); /* h(t=0) = 0 */
        for (int t = 0; t < TT; ++t) {
            const float* hin = (t & 1) ? hB : hA;
            float* hout = (t & 1) ? hA : hB;
            k_step_slow<<<128, 256, 0, stream>>>(x + (size_t)t * BB * II, pad + t * BB,
                                                 w_ih, w_hh, b_ih, b_hh, hin, hout, out, t);
        }
    }
}

// Round 2
// 2620.590 us; speedup vs baseline: 2.0691x; 1.3145x over previous
//
#include <hip/hip_runtime.h>

#define TT 512
#define BB 32
#define II 512
#define HH 1024
#define G3 3072
#define TBH (TT * BB * HH) /* 16777216 */

typedef __attribute__((ext_vector_type(8))) short short8;
typedef __attribute__((ext_vector_type(4))) float f32x4;

__device__ __forceinline__ float sigmoidf_(float x) {
    return 1.f / (1.f + __expf(-x));
}
__device__ __forceinline__ float tanh_fast(float x) {
    float e2 = __expf(2.f * x);
    return 1.f - 2.f / (e2 + 1.f);
}
/* round-to-nearest-even f32 -> bf16 (top 16 bits) */
__device__ __forceinline__ unsigned rne16(float x) {
    unsigned u = __float_as_uint(x);
    return (u + 0x7FFFu + ((u >> 16) & 1u)) >> 16;
}
/* split x = hi + lo (both bf16); |x - hi - lo| <= 2^-17 |x| */
__device__ __forceinline__ void bsplit(float x, unsigned& hi, unsigned& lo) {
    unsigned h16 = rne16(x);
    float xh = __uint_as_float(h16 << 16);
    hi = h16;
    lo = rne16(x - xh); /* x - xh is exact (Sterbenz) */
}

/* ---- gi = A(M x 512) @ w_ih(512 x 3072) + b_ih ---- */
__global__ __launch_bounds__(256) void k_gi_gemm(const float* __restrict__ A,
                                                 const float* __restrict__ B,
                                                 const float* __restrict__ bias,
                                                 float* __restrict__ C, int M) {
    __shared__ float As[8][128];
    __shared__ float Bs[8][128];
    int tid = threadIdx.x;
    int m0 = blockIdx.x * 128;
    int n0 = blockIdx.y * 128;
    int tx = tid & 15, ty = tid >> 4;
    int rowA = tid >> 1, kA = (tid & 1) * 4;
    int kB = tid >> 5, cB = (tid & 31) * 4;
    float acc[8][8] = {};
    for (int k0 = 0; k0 < 512; k0 += 8) {
        int rg = m0 + rowA;
        if (rg > M - 1) rg = M - 1;
        float4 a4 = *(const float4*)(A + (size_t)rg * 512 + k0 + kA);
        float4 b4 = *(const float4*)(B + (size_t)(k0 + kB) * G3 + n0 + cB);
        __syncthreads();
        As[kA + 0][rowA] = a4.x;
        As[kA + 1][rowA] = a4.y;
        As[kA + 2][rowA] = a4.z;
        As[kA + 3][rowA] = a4.w;
        *(float4*)&Bs[kB][cB] = b4;
        __syncthreads();
#pragma unroll
        for (int kk = 0; kk < 8; ++kk) {
            float4 a0 = *(const float4*)&As[kk][ty * 8];
            float4 a1 = *(const float4*)&As[kk][ty * 8 + 4];
            float4 b0 = *(const float4*)&Bs[kk][tx * 8];
            float4 b1 = *(const float4*)&Bs[kk][tx * 8 + 4];
            float av[8] = {a0.x, a0.y, a0.z, a0.w, a1.x, a1.y, a1.z, a1.w};
            float bv[8] = {b0.x, b0.y, b0.z, b0.w, b1.x, b1.y, b1.z, b1.w};
#pragma unroll
            for (int i = 0; i < 8; ++i)
#pragma unroll
                for (int j = 0; j < 8; ++j) acc[i][j] += av[i] * bv[j];
        }
    }
    float4 bi0 = *(const float4*)(bias + n0 + tx * 8);
    float4 bi1 = *(const float4*)(bias + n0 + tx * 8 + 4);
    float bb[8] = {bi0.x, bi0.y, bi0.z, bi0.w, bi1.x, bi1.y, bi1.z, bi1.w};
#pragma unroll
    for (int i = 0; i < 8; ++i) {
        int row = m0 + ty * 8 + i;
        if (row < M) {
            float4 s0 = {acc[i][0] + bb[0], acc[i][1] + bb[1], acc[i][2] + bb[2], acc[i][3] + bb[3]};
            float4 s1 = {acc[i][4] + bb[4], acc[i][5] + bb[5], acc[i][6] + bb[6], acc[i][7] + bb[7]};
            *(float4*)(C + (size_t)row * G3 + n0 + tx * 8) = s0;
            *(float4*)(C + (size_t)row * G3 + n0 + tx * 8 + 4) = s1;
        }
    }
}

/* ---- persistent recurrent kernel, v3: MFMA bf16x3 ----
   grid 256 = 64 h-col-groups x 4 batch-octets; block 512 thr = 8 waves.
   h(t) lives in out[t] (f32); out pre-memset to 0xFFFFFFFF (NaN sentinel,
   unreachable since |h|<1): data is its own readiness flag (v2 scheme).
   NEW: the recurrent GEMV h[8x1024] @ W_hh[1024x48] runs on the matrix
   pipe as mfma_f32_16x16x32_bf16 with an error-free-to-f32 bf16x3 split:
   h*w ~= h_hi*w_hi + h_hi*w_lo + h_lo*w_hi  (dropped h_lo*w_lo <= 2^-18).
   Each wave owns a 128-wide k-slice: weights pre-split into 96 VGPRs of
   bf16 frags; staged h is converted to packed bf16 hi/lo pairs in LDS
   with a T2-style XOR swizzle (p ^= (row&7)<<2) so the 16-lane same-col
   A-frag read is bank-conflict-free; exact f32 h kept in LDS for the
   padding-hold path. MFMA C/D layout: col=lane&15, row=(lane>>4)*4+reg
   (m89-verified); A-rows 8..15 are zeroed once (M=16 pad for 8 batches). */
__global__ __launch_bounds__(512, 2) void k_persist(const float* __restrict__ w_hh,
                                                    const float* __restrict__ gi,
                                                    const float* __restrict__ pad,
                                                    const float* __restrict__ b_hh,
                                                    float* __restrict__ out,
                                                    int t0, int ct) {
    __shared__ unsigned Ahi[16 * 512]; /* bf16-hi pairs, rows 8..15 = 0 */
    __shared__ unsigned Alo[16 * 512]; /* bf16-lo pairs */
    __shared__ float hf[8 * 1032];     /* exact f32 h(t-1), row stride 1032 */
    __shared__ float part[8 * 576];    /* [wave][g*192 + col*12 + b] */

    int tid = threadIdx.x;
    int hg = blockIdx.x & 63, boct = blockIdx.x >> 6;
    int hc0 = hg << 4;
    int b0 = boct << 3;

    int wk = tid >> 6;  /* wave id = staged batch = k-slice [wk*128, wk*128+128) */
    int lane = tid & 63;
    int kg = lane >> 4; /* k-group within frag */
    int cx = lane & 15; /* A-row (batch) for MFMA reads; C/D col for writes */

    /* ---- one-time: weights -> bf16 hi/lo frags in VGPRs (96 regs) ---- */
    short8 Bh[3][4], Bl[3][4];
#pragma unroll
    for (int g = 0; g < 3; ++g)
#pragma unroll
        for (int kf = 0; kf < 4; ++kf) {
            unsigned hh_[8], ll_[8];
#pragma unroll
            for (int j = 0; j < 8; ++j) {
                int k = wk * 128 + kf * 32 + kg * 8 + j;
                float w = w_hh[(size_t)k * G3 + hc0 + cx + g * HH];
                bsplit(w, hh_[j], ll_[j]);
            }
            union { unsigned u[4]; short8 s; } ph, pl;
#pragma unroll
            for (int r = 0; r < 4; ++r) {
                ph.u[r] = hh_[2 * r] | (hh_[2 * r + 1] << 16);
                pl.u[r] = ll_[2 * r] | (ll_[2 * r + 1] << 16);
            }
            Bh[g][kf] = ph.s;
            Bl[g][kf] = pl.s;
        }

    /* zero A rows 8..15 (M-pad) once */
    for (int i = tid; i < 8 * 512; i += 512) {
        Ahi[8 * 512 + i] = 0;
        Alo[8 * 512 + i] = 0;
    }

    /* gate-thread constants (tid<128: col = hc0+cg, batch = b2) */
    int cg = tid & 15, b2 = tid >> 4;
    int col = hc0 + cg;
    int bg = b0 + b2;
    float bhr = 0.f, bhz = 0.f, bhn = 0.f;
    if (tid < 128) {
        bhr = b_hh[col];
        bhz = b_hh[col + HH];
        bhn = b_hh[col + 2 * HH];
    }

    int swz = wk << 2; /* stage-side row swizzle ((row&7)<<2), row = wk */

    for (int s = 0; s < ct; ++s) {
        int t = t0 + s;

        /* prefetch gi + pad (consumed in gates phase) */
        float gir = 0.f, giz = 0.f, gin = 0.f, pv = 0.f;
        if (tid < 128) {
            const float* gp = gi + ((size_t)s * BB + bg) * G3 + col;
            gir = gp[0];
            giz = gp[HH];
            gin = gp[2 * HH];
            pv = pad[t * BB + bg];
        }

        /* stage h(t-1): poll out[t-1] (sentinel = not yet written), then
           split each f32 into bf16 hi/lo pairs -> swizzled LDS, and keep
           the exact f32 in hf for the padding-hold path. */
        if (t == 0) {
#pragma unroll
            for (int i = 0; i < 8; ++i) {
                int p = lane + 64 * i;
                Ahi[wk * 512 + (p ^ swz)] = 0;
                Alo[wk * 512 + (p ^ swz)] = 0;
                *(unsigned long long*)&hf[wk * 1032 + 2 * p] = 0ull;
            }
        } else {
            const unsigned long long* hp =
                (const unsigned long long*)(out + (size_t)(t - 1) * (BB * HH) +
                                            (size_t)(b0 + wk) * HH) + lane;
            unsigned long long v[8];
#pragma unroll
            for (int i = 0; i < 8; ++i)
                v[i] = __hip_atomic_load(hp + i * 64, __ATOMIC_RELAXED,
                                         __HIP_MEMORY_SCOPE_AGENT);
            for (;;) {
                int bad = 0;
#pragma unroll
                for (int i = 0; i < 8; ++i) {
                    unsigned lo = (unsigned)v[i];
                    unsigned hi = (unsigned)(v[i] >> 32);
                    if (lo == 0xFFFFFFFFu || hi == 0xFFFFFFFFu) bad |= (1 << i);
                }
                if (!bad) break;
                __builtin_amdgcn_s_sleep(1);
#pragma unroll
                for (int i = 0; i < 8; ++i)
                    if (bad & (1 << i))
                        v[i] = __hip_atomic_load(hp + i * 64, __ATOMIC_RELAXED,
                                                 __HIP_MEMORY_SCOPE_AGENT);
            }
#pragma unroll
            for (int i = 0; i < 8; ++i) {
                int p = lane + 64 * i;
                float xe = __uint_as_float((unsigned)v[i]);
                float xo = __uint_as_float((unsigned)(v[i] >> 32));
                unsigned he, le, ho, lo_;
                bsplit(xe, he, le);
                bsplit(xo, ho, lo_);
                Ahi[wk * 512 + (p ^ swz)] = he | (ho << 16);
                Alo[wk * 512 + (p ^ swz)] = le | (lo_ << 16);
                *(unsigned long long*)&hf[wk * 1032 + 2 * p] = v[i];
            }
        }
        __syncthreads();

        /* MFMA phase: per wave 4 k-frags x 3 gates x 3 (bf16x3) = 36 MFMA */
        f32x4 acc[3];
        acc[0] = (f32x4){0.f, 0.f, 0.f, 0.f};
        acc[1] = (f32x4){0.f, 0.f, 0.f, 0.f};
        acc[2] = (f32x4){0.f, 0.f, 0.f, 0.f};
        {
            int row = cx;               /* A row = batch (8..15 read zeros) */
            int r7s = (row & 7) << 2;   /* read-side swizzle matches stage */
#pragma unroll
            for (int kf = 0; kf < 4; ++kf) {
                int p0 = wk * 64 + kf * 16 + kg * 4;
                short8 ah = *(const short8*)&Ahi[row * 512 + (p0 ^ r7s)];
                short8 al = *(const short8*)&Alo[row * 512 + (p0 ^ r7s)];
#pragma unroll
                for (int g = 0; g < 3; ++g) {
                    acc[g] = __builtin_amdgcn_mfma_f32_16x16x32_bf16(ah, Bh[g][kf], acc[g], 0, 0, 0);
                    acc[g] = __builtin_amdgcn_mfma_f32_16x16x32_bf16(ah, Bl[g][kf], acc[g], 0, 0, 0);
                    acc[g] = __builtin_amdgcn_mfma_f32_16x16x32_bf16(al, Bh[g][kf], acc[g], 0, 0, 0);
                }
            }
        }
        /* partial C: lanes 0..31 hold valid batch rows 0..7 */
        if (lane < 32) {
            int r0 = (lane >> 4) * 4;
#pragma unroll
            for (int g = 0; g < 3; ++g)
                *(f32x4*)&part[wk * 576 + g * 192 + cx * 12 + r0] = acc[g];
        }
        __syncthreads();

        /* gates: 128 threads reduce 8 wave-partials per (g,b,col) */
        if (tid < 128) {
            float gh0 = 0.f, gh1 = 0.f, gh2 = 0.f;
#pragma unroll
            for (int w = 0; w < 8; ++w) {
                int base = w * 576 + cg * 12 + b2;
                gh0 += part[base];
                gh1 += part[base + 192];
                gh2 += part[base + 384];
            }
            float hprev = hf[b2 * 1032 + col];
            float r = sigmoidf_(gir + gh0 + bhr);
            float z = sigmoidf_(giz + gh1 + bhz);
            float n = tanh_fast(gin + r * (gh2 + bhn));
            float hnew = (1.f - z) * n + z * hprev;
            hnew = pv * hprev + (1.f - pv) * hnew;
            size_t oo = (size_t)t * (BB * HH) + (size_t)bg * HH + col;
            /* self-signaling store: straight to L3, consumers poll it */
            __hip_atomic_store(out + oo, hnew, __ATOMIC_RELAXED,
                               __HIP_MEMORY_SCOPE_AGENT);
            out[(size_t)TBH + oo] = hnew;
        }
        /* WAR guard: LDS fully consumed before next step restages */
        __syncthreads();
    }
}

/* ---- emergency fallback if workspace is tiny: fused, slow, correct ---- */
__global__ __launch_bounds__(256) void k_step_slow(const float* __restrict__ x_t,
                                                   const float* __restrict__ pad_t,
                                                   const float* __restrict__ w_ih,
                                                   const float* __restrict__ w_hh,
                                                   const float* __restrict__ b_ih,
                                                   const float* __restrict__ b_hh,
                                                   const float* __restrict__ h_in,
                                                   float* __restrict__ h_out,
                                                   float* __restrict__ out, int t) {
    int g = blockIdx.x * 256 + threadIdx.x;
    int b = g >> 10, j = g & 1023;
    float gir = b_ih[j], giz = b_ih[j + HH], gin = b_ih[j + 2 * HH];
    for (int k = 0; k < II; ++k) {
        float xv = x_t[b * II + k];
        const float* wr = w_ih + (size_t)k * G3;
        gir += xv * wr[j];
        giz += xv * wr[j + HH];
        gin += xv * wr[j + 2 * HH];
    }
    float ghr = b_hh[j], ghz = b_hh[j + HH], ghn = b_hh[j + 2 * HH];
    for (int k = 0; k < HH; ++k) {
        float hv = h_in[b * HH + k];
        const float* wr = w_hh + (size_t)k * G3;
        ghr += hv * wr[j];
        ghz += hv * wr[j + HH];
        ghn += hv * wr[j + 2 * HH];
    }
    float hprev = h_in[b * HH + j];
    float p = pad_t[b];
    float r = sigmoidf_(gir + ghr);
    float z = sigmoidf_(giz + ghz);
    float n = tanh_fast(gin + r * ghn);
    float hnew = (1.f - z) * n + z * hprev;
    hnew = p * hprev + (1.f - p) * hnew;
    size_t o = (size_t)b * HH + j;
    h_out[o] = hnew;
    size_t oo = (size_t)t * (BB * HH) + o;
    out[oo] = hnew;
    out[(size_t)TBH + oo] = hnew;
}

extern "C" void kernel_launch(void* const* d_in, const int* in_sizes, int n_in,
                              void* d_out, int out_size, void* d_ws, size_t ws_size,
                              hipStream_t stream) {
    const float* x    = (const float*)d_in[0];
    const float* pad  = (const float*)d_in[1];
    const float* w_ih = (const float*)d_in[2];
    const float* w_hh = (const float*)d_in[3];
    const float* b_ih = (const float*)d_in[4];
    const float* b_hh = (const float*)d_in[5];
    float* out = (float*)d_out;

    char* wsb = (char*)d_ws;
    float* hA = (float*)wsb;            /* 128 KB (fallback only) */
    float* hB = (float*)(wsb + 131072); /* 128 KB (fallback only) */
    float* gi = (float*)(wsb + 262144); /* Tc * 32 * 3072 * 4 B */

    long long cap = (long long)ws_size - 262144LL;
    int Tc = cap > 0 ? (int)(cap / 393216LL) : 0;
    if (Tc > TT) Tc = TT;

    if (Tc >= 1) {
        /* sentinel-fill the h-history region (first copy of out): 0xFFFFFFFF
           is float NaN, unreachable since |h| < 1 always */
        hipMemsetAsync(out, 0xFF, (size_t)TBH * 4, stream);
        for (int t0 = 0; t0 < TT; t0 += Tc) {
            int ctn = (TT - t0 < Tc) ? (TT - t0) : Tc;
            int M = ctn * BB;
            dim3 g((M + 127) / 128, 24);
            k_gi_gemm<<<g, 256, 0, stream>>>(x + (size_t)t0 * BB * II, w_ih, b_ih, gi, M);
            k_persist<<<256, 512, 0, stream>>>(w_hh, gi, pad, b_hh, out, t0, ctn);
        }
    } else {
        hipMemsetAsync(hA, 0, 131072, stream); /* h(t=0) = 0 */
        for (int t = 0; t < TT; ++t) {
            const float* hin = (t & 1) ? hB : hA;
            float* hout = (t & 1) ? hA : hB;
            k_step_slow<<<128, 256, 0, stream>>>(x + (size_t)t * BB * II, pad + t * BB,
                                                 w_ih, w_hh, b_ih, b_hh, hin, hout, out, t);
        }
    }
}